// Round 1
// baseline (625.182 us; speedup 1.0000x reference)
//
#include <hip/hip_runtime.h>

#define NN 50000
#define D 128

// ---------------- preprocessing kernels ----------------

__global__ void zero_i32(int* __restrict__ p, int n) {
    int i = blockIdx.x * blockDim.x + threadIdx.x;
    if (i < n) p[i] = 0;
}

__global__ void count_kernel(const int* __restrict__ dst, int* __restrict__ cnt, int E) {
    int e = blockIdx.x * blockDim.x + threadIdx.x;
    if (e < E) atomicAdd(&cnt[dst[e]], 1);
}

__global__ void dinv_kernel(const int* __restrict__ cnt, float* __restrict__ dinv, int n) {
    int i = blockIdx.x * blockDim.x + threadIdx.x;
    if (i < n) dinv[i] = rsqrtf((float)cnt[i] + 1.0f);  // +1 self-loop, deg>=1 always
}

// single-block exclusive scan over cnt[0..n-1]; writes rowstart[0..n] and cursor[0..n-1]
__global__ void scan_kernel(const int* __restrict__ cnt, int* __restrict__ rowstart,
                            int* __restrict__ cursor, int n) {
    __shared__ int smem[1024];
    __shared__ int carry;
    if (threadIdx.x == 0) carry = 0;
    __syncthreads();
    for (int base = 0; base < n + 1; base += 1024) {
        int i = base + (int)threadIdx.x;
        int v = (i < n) ? cnt[i] : 0;
        smem[threadIdx.x] = v;
        __syncthreads();
        for (int off = 1; off < 1024; off <<= 1) {
            int t = 0;
            if ((int)threadIdx.x >= off) t = smem[threadIdx.x - off];
            __syncthreads();
            if ((int)threadIdx.x >= off) smem[threadIdx.x] += t;
            __syncthreads();
        }
        int incl  = smem[threadIdx.x];
        int total = smem[1023];
        int excl  = incl - v;
        if (i <= n) {
            int val = carry + excl;
            rowstart[i] = val;
            if (i < n) cursor[i] = val;
        }
        __syncthreads();                    // all carry reads done
        if (threadIdx.x == 0) carry += total;
        __syncthreads();
    }
}

__global__ void scatter_kernel(const int* __restrict__ srcA, const int* __restrict__ dstA,
                               int* __restrict__ cursor, int* __restrict__ csr_src, int E) {
    int e = blockIdx.x * blockDim.x + threadIdx.x;
    if (e < E) {
        int d = dstA[e];
        int pos = atomicAdd(&cursor[d], 1);
        csr_src[pos] = srcA[e];
    }
}

// ---------------- dense GEMM: H[M,128] = X[M,128] @ W[128,128] ----------------
// W staged in LDS (64 KB); 128x128 block tile; 8x8 register tile per thread.
__global__ __launch_bounds__(256, 2) void gemm_kernel(const float* __restrict__ X,
                                                      const float* __restrict__ W,
                                                      float* __restrict__ H, int M) {
    __shared__ float Ws[D * D];
    {
        const float4* W4 = (const float4*)W;
        float4* Ws4 = (float4*)Ws;
        for (int i = threadIdx.x; i < D * D / 4; i += 256) Ws4[i] = W4[i];
    }
    __syncthreads();

    const int row0 = blockIdx.x * 128 + (threadIdx.x >> 4) * 8;
    const int c0   = (threadIdx.x & 15) * 8;

    float acc[8][8];
#pragma unroll
    for (int r = 0; r < 8; r++)
#pragma unroll
        for (int c = 0; c < 8; c++) acc[r][c] = 0.0f;

    for (int kb = 0; kb < D; kb += 4) {
        float4 xr[8];
#pragma unroll
        for (int r = 0; r < 8; r++) {
            int rr = row0 + r;
            xr[r] = (rr < M) ? *(const float4*)(X + (size_t)rr * D + kb)
                             : make_float4(0.f, 0.f, 0.f, 0.f);
        }
#pragma unroll
        for (int kk = 0; kk < 4; kk++) {
            const float4 w0 = *(const float4*)(Ws + (kb + kk) * D + c0);
            const float4 w1 = *(const float4*)(Ws + (kb + kk) * D + c0 + 4);
            float wv[8] = {w0.x, w0.y, w0.z, w0.w, w1.x, w1.y, w1.z, w1.w};
#pragma unroll
            for (int r = 0; r < 8; r++) {
                float xv = (&xr[r].x)[kk];
#pragma unroll
                for (int c = 0; c < 8; c++) acc[r][c] = fmaf(xv, wv[c], acc[r][c]);
            }
        }
    }

#pragma unroll
    for (int r = 0; r < 8; r++) {
        int rr = row0 + r;
        if (rr < M) {
            *(float4*)(H + (size_t)rr * D + c0)     = make_float4(acc[r][0], acc[r][1], acc[r][2], acc[r][3]);
            *(float4*)(H + (size_t)rr * D + c0 + 4) = make_float4(acc[r][4], acc[r][5], acc[r][6], acc[r][7]);
        }
    }
}

// ---------------- aggregation: out[i] = dinv[i]*(sum_e dinv[src]*h[src] + dinv[i]*h[i]) + b ----------------
// one wave (64 lanes) per node; lane handles float2 of the 128 features.
__global__ __launch_bounds__(256) void agg_kernel(const float* __restrict__ H,
                                                  const float* __restrict__ dinv,
                                                  const int* __restrict__ rowstart,
                                                  const int* __restrict__ csr,
                                                  const float* __restrict__ bias,
                                                  float* __restrict__ OUT,
                                                  int n, int do_relu, int zero0) {
    int node = blockIdx.x * 4 + (threadIdx.x >> 6);
    if (node >= n) return;
    int lane = threadIdx.x & 63;
    int col = lane * 2;

    float di = dinv[node];
    float2 hs = *(const float2*)(H + (size_t)node * D + col);
    float ax = di * hs.x;
    float ay = di * hs.y;

    int s = rowstart[node];
    int e = rowstart[node + 1];
    for (int p = s; p < e; p++) {
        int src = csr[p];
        float w = dinv[src];
        float2 hv = *(const float2*)(H + (size_t)src * D + col);
        ax = fmaf(w, hv.x, ax);
        ay = fmaf(w, hv.y, ay);
    }

    float2 b = *(const float2*)(bias + col);
    float rx = fmaf(di, ax, b.x);
    float ry = fmaf(di, ay, b.y);
    if (do_relu) { rx = fmaxf(rx, 0.f); ry = fmaxf(ry, 0.f); }
    if (zero0 && node == 0) { rx = 0.f; ry = 0.f; }
    *(float2*)(OUT + (size_t)node * D + col) = make_float2(rx, ry);
}

// ---------------- launch ----------------

extern "C" void kernel_launch(void* const* d_in, const int* in_sizes, int n_in,
                              void* d_out, int out_size, void* d_ws, size_t ws_size,
                              hipStream_t stream) {
    const float* emb = (const float*)d_in[0];
    const float* W1  = (const float*)d_in[1];
    const float* b1  = (const float*)d_in[2];
    const float* W2  = (const float*)d_in[3];
    const float* b2  = (const float*)d_in[4];
    const float* W3  = (const float*)d_in[5];
    const float* b3  = (const float*)d_in[6];
    const int*   ei  = (const int*)d_in[7];

    const int E = in_sizes[7] / 2;
    const int* srcA = ei;
    const int* dstA = ei + E;
    float* out = (float*)d_out;

    char* ws = (char*)d_ws;
    size_t off = 0;
    auto alloc = [&](size_t bytes) -> void* {
        void* p = ws + off;
        off = (off + bytes + 255) & ~(size_t)255;
        return p;
    };
    float* h    = (float*)alloc((size_t)NN * D * 4);
    float* xb   = (float*)alloc((size_t)NN * D * 4);
    float* dinv = (float*)alloc((size_t)NN * 4);
    int* cnt      = (int*)alloc((size_t)(NN + 1) * 4);
    int* rowstart = (int*)alloc((size_t)(NN + 1) * 4);
    int* cursor   = (int*)alloc((size_t)NN * 4);
    int* csr      = (int*)alloc((size_t)E * 4);

    const int T = 256;
    // preprocessing
    zero_i32<<<(NN + 1 + T - 1) / T, T, 0, stream>>>(cnt, NN + 1);
    count_kernel<<<(E + T - 1) / T, T, 0, stream>>>(dstA, cnt, E);
    dinv_kernel<<<(NN + T - 1) / T, T, 0, stream>>>(cnt, dinv, NN);
    scan_kernel<<<1, 1024, 0, stream>>>(cnt, rowstart, cursor, NN);
    scatter_kernel<<<(E + T - 1) / T, T, 0, stream>>>(srcA, dstA, cursor, csr, E);

    const int gemm_grid = (NN + 127) / 128;
    const int agg_grid  = (NN + 3) / 4;

    // layer 1
    gemm_kernel<<<gemm_grid, T, 0, stream>>>(emb, W1, h, NN);
    agg_kernel<<<agg_grid, T, 0, stream>>>(h, dinv, rowstart, csr, b1, xb, NN, 1, 0);
    // layer 2
    gemm_kernel<<<gemm_grid, T, 0, stream>>>(xb, W2, h, NN);
    agg_kernel<<<agg_grid, T, 0, stream>>>(h, dinv, rowstart, csr, b2, xb, NN, 1, 0);
    // layer 3
    gemm_kernel<<<gemm_grid, T, 0, stream>>>(xb, W3, h, NN);
    agg_kernel<<<agg_grid, T, 0, stream>>>(h, dinv, rowstart, csr, b3, out, NN, 0, 1);
}

// Round 2
// 477.299 us; speedup vs baseline: 1.3098x; 1.3098x over previous
//
#include <hip/hip_runtime.h>

#define NN 50000
#define D 128
#define SCAN_BS 512

// ---------------- preprocessing kernels ----------------

__global__ void zero_i32(int* __restrict__ p, int n) {
    int i = blockIdx.x * blockDim.x + threadIdx.x;
    if (i < n) p[i] = 0;
}

__global__ void count_kernel(const int* __restrict__ dst, int* __restrict__ cnt, int E) {
    int e = blockIdx.x * blockDim.x + threadIdx.x;
    if (e < E) atomicAdd(&cnt[dst[e]], 1);
}

__global__ void dinv_kernel(const int* __restrict__ cnt, float* __restrict__ dinv, int n) {
    int i = blockIdx.x * blockDim.x + threadIdx.x;
    if (i < n) dinv[i] = rsqrtf((float)cnt[i] + 1.0f);  // +1 self-loop, deg>=1 always
}

// ---- multi-block exclusive scan over cnt[0..NN-1], producing rowstart[0..NN] ----
// scan1: per-block inclusive scan; writes block-local EXCLUSIVE value to rs, block total to bsum
__global__ __launch_bounds__(SCAN_BS) void scan1_kernel(const int* __restrict__ cnt,
                                                        int* __restrict__ rs,
                                                        int* __restrict__ bsum, int n) {
    __shared__ int sm[SCAN_BS];
    int i = blockIdx.x * SCAN_BS + threadIdx.x;
    int v = (i < n - 1) ? cnt[i] : 0;  // element n-1 (== index NN) is the sentinel, value 0
    sm[threadIdx.x] = v;
    __syncthreads();
#pragma unroll
    for (int off = 1; off < SCAN_BS; off <<= 1) {
        int t = 0;
        if ((int)threadIdx.x >= off) t = sm[threadIdx.x - off];
        __syncthreads();
        if ((int)threadIdx.x >= off) sm[threadIdx.x] += t;
        __syncthreads();
    }
    int incl = sm[threadIdx.x];
    if (i < n) rs[i] = incl - v;
    if (threadIdx.x == SCAN_BS - 1) bsum[blockIdx.x] = incl;
}

// scan2: exclusive scan of bsum[0..g-1] (g <= 128), single block of 128 threads
__global__ __launch_bounds__(128) void scan2_kernel(int* __restrict__ bsum, int g) {
    __shared__ int sm[128];
    int v = ((int)threadIdx.x < g) ? bsum[threadIdx.x] : 0;
    sm[threadIdx.x] = v;
    __syncthreads();
#pragma unroll
    for (int off = 1; off < 128; off <<= 1) {
        int t = 0;
        if ((int)threadIdx.x >= off) t = sm[threadIdx.x - off];
        __syncthreads();
        if ((int)threadIdx.x >= off) sm[threadIdx.x] += t;
        __syncthreads();
    }
    if ((int)threadIdx.x < g) bsum[threadIdx.x] = sm[threadIdx.x] - v;  // exclusive
}

// scan3: add block offsets; write final rowstart and cursor
__global__ __launch_bounds__(SCAN_BS) void scan3_kernel(int* __restrict__ rs,
                                                        const int* __restrict__ bsum,
                                                        int* __restrict__ cursor, int n) {
    int i = blockIdx.x * SCAN_BS + threadIdx.x;
    if (i < n) {
        int val = rs[i] + bsum[blockIdx.x];
        rs[i] = val;
        if (i < n - 1) cursor[i] = val;
    }
}

__global__ void scatter_kernel(const int* __restrict__ srcA, const int* __restrict__ dstA,
                               int* __restrict__ cursor, int* __restrict__ csr_src, int E) {
    int e = blockIdx.x * blockDim.x + threadIdx.x;
    if (e < E) {
        int d = dstA[e];
        int pos = atomicAdd(&cursor[d], 1);
        csr_src[pos] = srcA[e];
    }
}

// ---------------- dense GEMM: H[M,128] = X[M,128] @ W[128,128] ----------------
__global__ __launch_bounds__(256, 2) void gemm_kernel(const float* __restrict__ X,
                                                      const float* __restrict__ W,
                                                      float* __restrict__ H, int M) {
    __shared__ float Ws[D * D];
    {
        const float4* W4 = (const float4*)W;
        float4* Ws4 = (float4*)Ws;
        for (int i = threadIdx.x; i < D * D / 4; i += 256) Ws4[i] = W4[i];
    }
    __syncthreads();

    const int row0 = blockIdx.x * 128 + (threadIdx.x >> 4) * 8;
    const int c0   = (threadIdx.x & 15) * 8;

    float acc[8][8];
#pragma unroll
    for (int r = 0; r < 8; r++)
#pragma unroll
        for (int c = 0; c < 8; c++) acc[r][c] = 0.0f;

    for (int kb = 0; kb < D; kb += 4) {
        float4 xr[8];
#pragma unroll
        for (int r = 0; r < 8; r++) {
            int rr = row0 + r;
            xr[r] = (rr < M) ? *(const float4*)(X + (size_t)rr * D + kb)
                             : make_float4(0.f, 0.f, 0.f, 0.f);
        }
#pragma unroll
        for (int kk = 0; kk < 4; kk++) {
            const float4 w0 = *(const float4*)(Ws + (kb + kk) * D + c0);
            const float4 w1 = *(const float4*)(Ws + (kb + kk) * D + c0 + 4);
            float wv[8] = {w0.x, w0.y, w0.z, w0.w, w1.x, w1.y, w1.z, w1.w};
#pragma unroll
            for (int r = 0; r < 8; r++) {
                float xv = (&xr[r].x)[kk];
#pragma unroll
                for (int c = 0; c < 8; c++) acc[r][c] = fmaf(xv, wv[c], acc[r][c]);
            }
        }
    }

#pragma unroll
    for (int r = 0; r < 8; r++) {
        int rr = row0 + r;
        if (rr < M) {
            *(float4*)(H + (size_t)rr * D + c0)     = make_float4(acc[r][0], acc[r][1], acc[r][2], acc[r][3]);
            *(float4*)(H + (size_t)rr * D + c0 + 4) = make_float4(acc[r][4], acc[r][5], acc[r][6], acc[r][7]);
        }
    }
}

// ---------------- aggregation ----------------
// out[i] = dinv[i]*(sum_e dinv[src]*h[src] + dinv[i]*h[i]) + b
// one wave per node; lane = float2 of 128 feats; edge loop unrolled x4 for MLP.
__global__ __launch_bounds__(256) void agg_kernel(const float* __restrict__ H,
                                                  const float* __restrict__ dinv,
                                                  const int* __restrict__ rowstart,
                                                  const int* __restrict__ csr,
                                                  const float* __restrict__ bias,
                                                  float* __restrict__ OUT,
                                                  int n, int do_relu, int zero0) {
    int node = blockIdx.x * 4 + (threadIdx.x >> 6);
    if (node >= n) return;
    int lane = threadIdx.x & 63;
    int col = lane * 2;

    float di = dinv[node];
    float2 hs = *(const float2*)(H + (size_t)node * D + col);
    float ax = di * hs.x;
    float ay = di * hs.y;
    float bx = 0.f, by = 0.f;

    int s = rowstart[node];
    int e = rowstart[node + 1];
    int p = s;
    for (; p + 4 <= e; p += 4) {
        int s0 = csr[p], s1 = csr[p + 1], s2 = csr[p + 2], s3 = csr[p + 3];
        float w0 = dinv[s0], w1 = dinv[s1], w2 = dinv[s2], w3 = dinv[s3];
        float2 h0 = *(const float2*)(H + (size_t)s0 * D + col);
        float2 h1 = *(const float2*)(H + (size_t)s1 * D + col);
        float2 h2 = *(const float2*)(H + (size_t)s2 * D + col);
        float2 h3 = *(const float2*)(H + (size_t)s3 * D + col);
        ax = fmaf(w0, h0.x, ax); ay = fmaf(w0, h0.y, ay);
        bx = fmaf(w1, h1.x, bx); by = fmaf(w1, h1.y, by);
        ax = fmaf(w2, h2.x, ax); ay = fmaf(w2, h2.y, ay);
        bx = fmaf(w3, h3.x, bx); by = fmaf(w3, h3.y, by);
    }
    for (; p < e; p++) {
        int src = csr[p];
        float w = dinv[src];
        float2 hv = *(const float2*)(H + (size_t)src * D + col);
        ax = fmaf(w, hv.x, ax);
        ay = fmaf(w, hv.y, ay);
    }
    ax += bx; ay += by;

    float2 b = *(const float2*)(bias + col);
    float rx = fmaf(di, ax, b.x);
    float ry = fmaf(di, ay, b.y);
    if (do_relu) { rx = fmaxf(rx, 0.f); ry = fmaxf(ry, 0.f); }
    if (zero0 && node == 0) { rx = 0.f; ry = 0.f; }
    *(float2*)(OUT + (size_t)node * D + col) = make_float2(rx, ry);
}

// ---------------- launch ----------------

extern "C" void kernel_launch(void* const* d_in, const int* in_sizes, int n_in,
                              void* d_out, int out_size, void* d_ws, size_t ws_size,
                              hipStream_t stream) {
    const float* emb = (const float*)d_in[0];
    const float* W1  = (const float*)d_in[1];
    const float* b1  = (const float*)d_in[2];
    const float* W2  = (const float*)d_in[3];
    const float* b2  = (const float*)d_in[4];
    const float* W3  = (const float*)d_in[5];
    const float* b3  = (const float*)d_in[6];
    const int*   ei  = (const int*)d_in[7];

    const int E = in_sizes[7] / 2;
    const int* srcA = ei;
    const int* dstA = ei + E;
    float* out = (float*)d_out;

    char* ws = (char*)d_ws;
    size_t off = 0;
    auto alloc = [&](size_t bytes) -> void* {
        void* p = ws + off;
        off = (off + bytes + 255) & ~(size_t)255;
        return p;
    };
    float* h    = (float*)alloc((size_t)NN * D * 4);
    float* xb   = (float*)alloc((size_t)NN * D * 4);
    float* dinv = (float*)alloc((size_t)NN * 4);
    int* cnt      = (int*)alloc((size_t)(NN + 1) * 4);
    int* rowstart = (int*)alloc((size_t)(NN + 1) * 4);
    int* cursor   = (int*)alloc((size_t)NN * 4);
    int* csr      = (int*)alloc((size_t)E * 4);
    int* bsum     = (int*)alloc(256 * 4);

    const int T = 256;
    const int n_scan = NN + 1;                       // rowstart has NN+1 entries
    const int scan_grid = (n_scan + SCAN_BS - 1) / SCAN_BS;  // 98 blocks <= 128

    // preprocessing
    zero_i32<<<(NN + 1 + T - 1) / T, T, 0, stream>>>(cnt, NN + 1);
    count_kernel<<<(E + T - 1) / T, T, 0, stream>>>(dstA, cnt, E);
    dinv_kernel<<<(NN + T - 1) / T, T, 0, stream>>>(cnt, dinv, NN);
    scan1_kernel<<<scan_grid, SCAN_BS, 0, stream>>>(cnt, rowstart, bsum, n_scan);
    scan2_kernel<<<1, 128, 0, stream>>>(bsum, scan_grid);
    scan3_kernel<<<scan_grid, SCAN_BS, 0, stream>>>(rowstart, bsum, cursor, n_scan);
    scatter_kernel<<<(E + T - 1) / T, T, 0, stream>>>(srcA, dstA, cursor, csr, E);

    const int gemm_grid = (NN + 127) / 128;
    const int agg_grid  = (NN + 3) / 4;

    // layer 1
    gemm_kernel<<<gemm_grid, T, 0, stream>>>(emb, W1, h, NN);
    agg_kernel<<<agg_grid, T, 0, stream>>>(h, dinv, rowstart, csr, b1, xb, NN, 1, 0);
    // layer 2
    gemm_kernel<<<gemm_grid, T, 0, stream>>>(xb, W2, h, NN);
    agg_kernel<<<agg_grid, T, 0, stream>>>(h, dinv, rowstart, csr, b2, xb, NN, 1, 0);
    // layer 3
    gemm_kernel<<<gemm_grid, T, 0, stream>>>(xb, W3, h, NN);
    agg_kernel<<<agg_grid, T, 0, stream>>>(h, dinv, rowstart, csr, b3, out, NN, 0, 1);
}

// Round 3
// 343.952 us; speedup vs baseline: 1.8176x; 1.3877x over previous
//
#include <hip/hip_runtime.h>

#define NN 50000
#define D 128
#define SCAN_BS 512

typedef __attribute__((ext_vector_type(8))) short bf16x8;
typedef __attribute__((ext_vector_type(16))) float f32x16;

static __device__ __forceinline__ short bf16_rne(float f) {
    unsigned u = __float_as_uint(f);
    unsigned r = (u + 0x7FFFu + ((u >> 16) & 1u)) >> 16;
    return (short)r;
}

// ---------------- preprocessing kernels ----------------

__global__ void zero_i32(int* __restrict__ p, int n) {
    int i = blockIdx.x * blockDim.x + threadIdx.x;
    if (i < n) p[i] = 0;
}

__global__ void count_kernel(const int* __restrict__ dst, int* __restrict__ cnt, int E) {
    int e = blockIdx.x * blockDim.x + threadIdx.x;
    if (e < E) atomicAdd(&cnt[dst[e]], 1);
}

__global__ void dinv_kernel(const int* __restrict__ cnt, float* __restrict__ dinv, int n) {
    int i = blockIdx.x * blockDim.x + threadIdx.x;
    if (i < n) dinv[i] = rsqrtf((float)cnt[i] + 1.0f);  // +1 self-loop
}

__global__ __launch_bounds__(SCAN_BS) void scan1_kernel(const int* __restrict__ cnt,
                                                        int* __restrict__ rs,
                                                        int* __restrict__ bsum, int n) {
    __shared__ int sm[SCAN_BS];
    int i = blockIdx.x * SCAN_BS + threadIdx.x;
    int v = (i < n - 1) ? cnt[i] : 0;
    sm[threadIdx.x] = v;
    __syncthreads();
#pragma unroll
    for (int off = 1; off < SCAN_BS; off <<= 1) {
        int t = 0;
        if ((int)threadIdx.x >= off) t = sm[threadIdx.x - off];
        __syncthreads();
        if ((int)threadIdx.x >= off) sm[threadIdx.x] += t;
        __syncthreads();
    }
    int incl = sm[threadIdx.x];
    if (i < n) rs[i] = incl - v;
    if (threadIdx.x == SCAN_BS - 1) bsum[blockIdx.x] = incl;
}

__global__ __launch_bounds__(128) void scan2_kernel(int* __restrict__ bsum, int g) {
    __shared__ int sm[128];
    int v = ((int)threadIdx.x < g) ? bsum[threadIdx.x] : 0;
    sm[threadIdx.x] = v;
    __syncthreads();
#pragma unroll
    for (int off = 1; off < 128; off <<= 1) {
        int t = 0;
        if ((int)threadIdx.x >= off) t = sm[threadIdx.x - off];
        __syncthreads();
        if ((int)threadIdx.x >= off) sm[threadIdx.x] += t;
        __syncthreads();
    }
    if ((int)threadIdx.x < g) bsum[threadIdx.x] = sm[threadIdx.x] - v;
}

__global__ __launch_bounds__(SCAN_BS) void scan3_kernel(int* __restrict__ rs,
                                                        const int* __restrict__ bsum,
                                                        int* __restrict__ cursor, int n) {
    int i = blockIdx.x * SCAN_BS + threadIdx.x;
    if (i < n) {
        int val = rs[i] + bsum[blockIdx.x];
        rs[i] = val;
        if (i < n - 1) cursor[i] = val;
    }
}

// scatter packs {src, bits(dinv[src])} so agg has no dependent dinv load
__global__ void scatter_kernel(const int* __restrict__ srcA, const int* __restrict__ dstA,
                               const float* __restrict__ dinv, int* __restrict__ cursor,
                               int2* __restrict__ csr2, int E) {
    int e = blockIdx.x * blockDim.x + threadIdx.x;
    if (e < E) {
        int d = dstA[e];
        int s = srcA[e];
        int pos = atomicAdd(&cursor[d], 1);
        csr2[pos] = make_int2(s, __float_as_int(dinv[s]));
    }
}

// ---------------- W fragment packing ----------------
// Wf layout (shorts): index = (((half*8 + ks)*4 + ct)*64 + lane)*8 + j
// fragment element: B[k = ks*16 + (lane>>5)*8 + j][n = ct*32 + (lane&31)]
struct alignas(16) S8 { short s[8]; };

__global__ __launch_bounds__(256) void pack_w_kernel(const float* __restrict__ W,
                                                     short* __restrict__ Wf) {
    int item = blockIdx.x * 256 + threadIdx.x;   // 4096 items total
    if (item >= 4096) return;
    int l    = item & 63;
    int ct   = (item >> 6) & 3;
    int ks   = (item >> 8) & 7;
    int half = item >> 11;
    int kbase = ks * 16 + (l >> 5) * 8;
    int n = ct * 32 + (l & 31);
    S8 out;
#pragma unroll
    for (int j = 0; j < 8; j++) {
        float w = W[(kbase + j) * D + n];
        short hi = bf16_rne(w);
        if (half == 0) {
            out.s[j] = hi;
        } else {
            float hif = __uint_as_float(((unsigned)(unsigned short)hi) << 16);
            float lo = w - hif;
            out.s[j] = (short)(__float_as_uint(lo) >> 16);
        }
    }
    ((S8*)Wf)[item] = out;
}

// ---------------- MFMA GEMM: H[M,128] = X[M,128] @ W[128,128] ----------------
// split-bf16: X@W ~= Xhi@Whi + Xhi@Wlo + Xlo@Whi (A split in-register from f32)
__global__ __launch_bounds__(256, 2) void gemm_mfma(const float* __restrict__ X,
                                                    const short* __restrict__ Wf,
                                                    float* __restrict__ H, int M) {
    __shared__ short Ws[32768];   // 64 KB fragment-packed W (hi | lo)
    {
        const int4* s = (const int4*)Wf;
        int4* d = (int4*)Ws;
        for (int i = threadIdx.x; i < 4096; i += 256) d[i] = s[i];
    }
    __syncthreads();

    const int wave = threadIdx.x >> 6;
    const int lane = threadIdx.x & 63;
    const int row0 = blockIdx.x * 128 + wave * 32;
    const int arow = min(row0 + (lane & 31), M - 1);
    const float* xrow = X + (size_t)arow * D + (lane >> 5) * 8;

    f32x16 acc[4] = {};

#pragma unroll
    for (int ks = 0; ks < 8; ks++) {
        const float* p = xrow + ks * 16;
        float4 fa = *(const float4*)p;
        float4 fb = *(const float4*)(p + 4);
        float f[8] = {fa.x, fa.y, fa.z, fa.w, fb.x, fb.y, fb.z, fb.w};
        bf16x8 ahi, alo;
#pragma unroll
        for (int j = 0; j < 8; j++) {
            unsigned u = __float_as_uint(f[j]);
            unsigned hb = u & 0xFFFF0000u;
            ahi[j] = (short)(u >> 16);
            float l = f[j] - __uint_as_float(hb);
            alo[j] = (short)(__float_as_uint(l) >> 16);
        }
#pragma unroll
        for (int ct = 0; ct < 4; ct++) {
            bf16x8 bhi = *(const bf16x8*)(Ws + (size_t)(((ks * 4 + ct) * 64) + lane) * 8);
            bf16x8 blo = *(const bf16x8*)(Ws + (size_t)(((ks * 4 + ct + 32) * 64) + lane) * 8);
            acc[ct] = __builtin_amdgcn_mfma_f32_32x32x16_bf16(ahi, bhi, acc[ct], 0, 0, 0);
            acc[ct] = __builtin_amdgcn_mfma_f32_32x32x16_bf16(ahi, blo, acc[ct], 0, 0, 0);
            acc[ct] = __builtin_amdgcn_mfma_f32_32x32x16_bf16(alo, bhi, acc[ct], 0, 0, 0);
        }
    }

    // C/D layout (verified m74/m101): col=lane&31, row=(r&3)+8*(r>>2)+4*(lane>>5)
    const int col0 = lane & 31;
    const int rbase = row0 + 4 * (lane >> 5);
#pragma unroll
    for (int ct = 0; ct < 4; ct++) {
#pragma unroll
        for (int r = 0; r < 16; r++) {
            int row = rbase + (r & 3) + 8 * (r >> 2);
            if (row < M) H[(size_t)row * D + ct * 32 + col0] = acc[ct][r];
        }
    }
}

// ---------------- aggregation ----------------
// out[i] = dinv[i]*(sum_e w_e*h[src_e] + dinv[i]*h[i]) + b ; w_e packed in csr2
__global__ __launch_bounds__(256) void agg_kernel(const float* __restrict__ H,
                                                  const float* __restrict__ dinv,
                                                  const int* __restrict__ rowstart,
                                                  const int2* __restrict__ csr2,
                                                  const float* __restrict__ bias,
                                                  float* __restrict__ OUT,
                                                  int n, int do_relu, int zero0) {
    int node = blockIdx.x * 4 + (threadIdx.x >> 6);
    if (node >= n) return;
    int lane = threadIdx.x & 63;
    int col = lane * 2;

    float di = dinv[node];
    float2 hs = *(const float2*)(H + (size_t)node * D + col);
    float ax = di * hs.x;
    float ay = di * hs.y;
    float bx = 0.f, by = 0.f;

    int s = rowstart[node];
    int e = rowstart[node + 1];
    int p = s;
    for (; p + 8 <= e; p += 8) {
        int2 sw[8];
#pragma unroll
        for (int j = 0; j < 8; j++) sw[j] = csr2[p + j];
        float2 hv[8];
#pragma unroll
        for (int j = 0; j < 8; j++)
            hv[j] = *(const float2*)(H + (size_t)sw[j].x * D + col);
#pragma unroll
        for (int j = 0; j < 8; j++) {
            float w = __int_as_float(sw[j].y);
            if (j & 1) { bx = fmaf(w, hv[j].x, bx); by = fmaf(w, hv[j].y, by); }
            else       { ax = fmaf(w, hv[j].x, ax); ay = fmaf(w, hv[j].y, ay); }
        }
    }
    for (; p + 4 <= e; p += 4) {
        int2 sw[4];
#pragma unroll
        for (int j = 0; j < 4; j++) sw[j] = csr2[p + j];
#pragma unroll
        for (int j = 0; j < 4; j++) {
            float w = __int_as_float(sw[j].y);
            float2 hv = *(const float2*)(H + (size_t)sw[j].x * D + col);
            if (j & 1) { bx = fmaf(w, hv.x, bx); by = fmaf(w, hv.y, by); }
            else       { ax = fmaf(w, hv.x, ax); ay = fmaf(w, hv.y, ay); }
        }
    }
    for (; p < e; p++) {
        int2 sw = csr2[p];
        float w = __int_as_float(sw.y);
        float2 hv = *(const float2*)(H + (size_t)sw.x * D + col);
        ax = fmaf(w, hv.x, ax);
        ay = fmaf(w, hv.y, ay);
    }
    ax += bx; ay += by;

    float2 b = *(const float2*)(bias + col);
    float rx = fmaf(di, ax, b.x);
    float ry = fmaf(di, ay, b.y);
    if (do_relu) { rx = fmaxf(rx, 0.f); ry = fmaxf(ry, 0.f); }
    if (zero0 && node == 0) { rx = 0.f; ry = 0.f; }
    *(float2*)(OUT + (size_t)node * D + col) = make_float2(rx, ry);
}

// ---------------- launch ----------------

extern "C" void kernel_launch(void* const* d_in, const int* in_sizes, int n_in,
                              void* d_out, int out_size, void* d_ws, size_t ws_size,
                              hipStream_t stream) {
    const float* emb = (const float*)d_in[0];
    const float* W1  = (const float*)d_in[1];
    const float* b1  = (const float*)d_in[2];
    const float* W2  = (const float*)d_in[3];
    const float* b2  = (const float*)d_in[4];
    const float* W3  = (const float*)d_in[5];
    const float* b3  = (const float*)d_in[6];
    const int*   ei  = (const int*)d_in[7];

    const int E = in_sizes[7] / 2;
    const int* srcA = ei;
    const int* dstA = ei + E;
    float* out = (float*)d_out;

    char* ws = (char*)d_ws;
    size_t off = 0;
    auto alloc = [&](size_t bytes) -> void* {
        void* p = ws + off;
        off = (off + bytes + 255) & ~(size_t)255;
        return p;
    };
    float* h    = (float*)alloc((size_t)NN * D * 4);
    float* xb   = (float*)alloc((size_t)NN * D * 4);
    float* dinv = (float*)alloc((size_t)NN * 4);
    int* cnt      = (int*)alloc((size_t)(NN + 1) * 4);
    int* rowstart = (int*)alloc((size_t)(NN + 1) * 4);
    int* cursor   = (int*)alloc((size_t)NN * 4);
    int2* csr2    = (int2*)alloc((size_t)E * 8);
    short* wf1    = (short*)alloc(4096 * 16);
    short* wf2    = (short*)alloc(4096 * 16);
    short* wf3    = (short*)alloc(4096 * 16);
    int* bsum     = (int*)alloc(256 * 4);

    const int T = 256;
    const int n_scan = NN + 1;
    const int scan_grid = (n_scan + SCAN_BS - 1) / SCAN_BS;

    // preprocessing
    zero_i32<<<(NN + 1 + T - 1) / T, T, 0, stream>>>(cnt, NN + 1);
    count_kernel<<<(E + T - 1) / T, T, 0, stream>>>(dstA, cnt, E);
    dinv_kernel<<<(NN + T - 1) / T, T, 0, stream>>>(cnt, dinv, NN);
    scan1_kernel<<<scan_grid, SCAN_BS, 0, stream>>>(cnt, rowstart, bsum, n_scan);
    scan2_kernel<<<1, 128, 0, stream>>>(bsum, scan_grid);
    scan3_kernel<<<scan_grid, SCAN_BS, 0, stream>>>(rowstart, bsum, cursor, n_scan);
    scatter_kernel<<<(E + T - 1) / T, T, 0, stream>>>(srcA, dstA, dinv, cursor, csr2, E);
    pack_w_kernel<<<16, T, 0, stream>>>(W1, wf1);
    pack_w_kernel<<<16, T, 0, stream>>>(W2, wf2);
    pack_w_kernel<<<16, T, 0, stream>>>(W3, wf3);

    const int gemm_grid = (NN + 127) / 128;
    const int agg_grid  = (NN + 3) / 4;

    // layer 1
    gemm_mfma<<<gemm_grid, T, 0, stream>>>(emb, wf1, h, NN);
    agg_kernel<<<agg_grid, T, 0, stream>>>(h, dinv, rowstart, csr2, b1, xb, NN, 1, 0);
    // layer 2
    gemm_mfma<<<gemm_grid, T, 0, stream>>>(xb, wf2, h, NN);
    agg_kernel<<<agg_grid, T, 0, stream>>>(h, dinv, rowstart, csr2, b2, xb, NN, 1, 0);
    // layer 3
    gemm_mfma<<<gemm_grid, T, 0, stream>>>(xb, wf3, h, NN);
    agg_kernel<<<agg_grid, T, 0, stream>>>(h, dinv, rowstart, csr2, b3, out, NN, 0, 1);
}

// Round 4
// 296.043 us; speedup vs baseline: 2.1118x; 1.1618x over previous
//
#include <hip/hip_runtime.h>
#include <hip/hip_fp16.h>

#define NN 50000
#define D 128
#define SCAN_BS 512

typedef __attribute__((ext_vector_type(8))) short bf16x8;
typedef __attribute__((ext_vector_type(16))) float f32x16;
typedef _Float16 h16;
typedef __attribute__((ext_vector_type(2))) _Float16 h16x2;

static __device__ __forceinline__ short bf16_rne(float f) {
    unsigned u = __float_as_uint(f);
    unsigned r = (u + 0x7FFFu + ((u >> 16) & 1u)) >> 16;
    return (short)r;
}

// ---------------- preprocessing kernels ----------------

__global__ void zero_i32(int* __restrict__ p, int n) {
    int i = blockIdx.x * blockDim.x + threadIdx.x;
    if (i < n) p[i] = 0;
}

__global__ void count_kernel(const int* __restrict__ dst, int* __restrict__ cnt, int E) {
    int e = blockIdx.x * blockDim.x + threadIdx.x;
    if (e < E) atomicAdd(&cnt[dst[e]], 1);
}

// scan1 + dinv fused: per-block inclusive scan of cnt; also writes dinv = rsqrt(cnt+1)
__global__ __launch_bounds__(SCAN_BS) void scan1_kernel(const int* __restrict__ cnt,
                                                        int* __restrict__ rs,
                                                        int* __restrict__ bsum,
                                                        float* __restrict__ dinv, int n) {
    __shared__ int sm[SCAN_BS];
    int i = blockIdx.x * SCAN_BS + threadIdx.x;
    int v = (i < n - 1) ? cnt[i] : 0;
    if (i < n - 1) dinv[i] = rsqrtf((float)v + 1.0f);  // +1 self-loop
    sm[threadIdx.x] = v;
    __syncthreads();
#pragma unroll
    for (int off = 1; off < SCAN_BS; off <<= 1) {
        int t = 0;
        if ((int)threadIdx.x >= off) t = sm[threadIdx.x - off];
        __syncthreads();
        if ((int)threadIdx.x >= off) sm[threadIdx.x] += t;
        __syncthreads();
    }
    int incl = sm[threadIdx.x];
    if (i < n) rs[i] = incl - v;
    if (threadIdx.x == SCAN_BS - 1) bsum[blockIdx.x] = incl;
}

__global__ __launch_bounds__(128) void scan2_kernel(int* __restrict__ bsum, int g) {
    __shared__ int sm[128];
    int v = ((int)threadIdx.x < g) ? bsum[threadIdx.x] : 0;
    sm[threadIdx.x] = v;
    __syncthreads();
#pragma unroll
    for (int off = 1; off < 128; off <<= 1) {
        int t = 0;
        if ((int)threadIdx.x >= off) t = sm[threadIdx.x - off];
        __syncthreads();
        if ((int)threadIdx.x >= off) sm[threadIdx.x] += t;
        __syncthreads();
    }
    if ((int)threadIdx.x < g) bsum[threadIdx.x] = sm[threadIdx.x] - v;
}

__global__ __launch_bounds__(SCAN_BS) void scan3_kernel(int* __restrict__ rs,
                                                        const int* __restrict__ bsum,
                                                        int* __restrict__ cursor, int n) {
    int i = blockIdx.x * SCAN_BS + threadIdx.x;
    if (i < n) {
        int val = rs[i] + bsum[blockIdx.x];
        rs[i] = val;
        if (i < n - 1) cursor[i] = val;
    }
}

// scatter packs {src, bits(dinv[src])} so agg has no dependent dinv load
__global__ void scatter_kernel(const int* __restrict__ srcA, const int* __restrict__ dstA,
                               const float* __restrict__ dinv, int* __restrict__ cursor,
                               int2* __restrict__ csr2, int E) {
    int e = blockIdx.x * blockDim.x + threadIdx.x;
    if (e < E) {
        int d = dstA[e];
        int s = srcA[e];
        int pos = atomicAdd(&cursor[d], 1);
        csr2[pos] = make_int2(s, __float_as_int(dinv[s]));
    }
}

// ---------------- W fragment packing (all 3 layers in one kernel) ----------------
// Wf layout (shorts): index = (((half*8 + ks)*4 + ct)*64 + lane)*8 + j
// fragment element: B[k = ks*16 + (lane>>5)*8 + j][n = ct*32 + (lane&31)]
struct alignas(16) S8 { short s[8]; };

__global__ __launch_bounds__(256) void pack_w3_kernel(const float* __restrict__ W1,
                                                      const float* __restrict__ W2,
                                                      const float* __restrict__ W3,
                                                      short* __restrict__ wf1,
                                                      short* __restrict__ wf2,
                                                      short* __restrict__ wf3) {
    int item = blockIdx.x * 256 + threadIdx.x;   // 3*4096 items
    if (item >= 3 * 4096) return;
    int which = item >> 12;
    const float* W = (which == 0) ? W1 : (which == 1) ? W2 : W3;
    short* Wf      = (which == 0) ? wf1 : (which == 1) ? wf2 : wf3;
    int it   = item & 4095;
    int l    = it & 63;
    int ct   = (it >> 6) & 3;
    int ks   = (it >> 8) & 7;
    int half = it >> 11;
    int kbase = ks * 16 + (l >> 5) * 8;
    int n = ct * 32 + (l & 31);
    S8 out;
#pragma unroll
    for (int j = 0; j < 8; j++) {
        float w = W[(kbase + j) * D + n];
        short hi = bf16_rne(w);
        if (half == 0) {
            out.s[j] = hi;
        } else {
            float hif = __uint_as_float(((unsigned)(unsigned short)hi) << 16);
            float lo = w - hif;
            out.s[j] = (short)(__float_as_uint(lo) >> 16);
        }
    }
    ((S8*)Wf)[it] = out;
}

// ---------------- MFMA GEMM: H[M,128](fp16) = X[M,128](f32) @ W[128,128] ----------------
// split-bf16: X@W ~= Xhi@Whi + Xhi@Wlo + Xlo@Whi; epilogue converts acc -> fp16
__global__ __launch_bounds__(256, 2) void gemm_mfma(const float* __restrict__ X,
                                                    const short* __restrict__ Wf,
                                                    h16* __restrict__ H, int M) {
    __shared__ short Ws[32768];   // 64 KB fragment-packed W (hi | lo)
    {
        const int4* s = (const int4*)Wf;
        int4* d = (int4*)Ws;
        for (int i = threadIdx.x; i < 4096; i += 256) d[i] = s[i];
    }
    __syncthreads();

    const int wave = threadIdx.x >> 6;
    const int lane = threadIdx.x & 63;
    const int row0 = blockIdx.x * 128 + wave * 32;
    const int arow = min(row0 + (lane & 31), M - 1);
    const float* xrow = X + (size_t)arow * D + (lane >> 5) * 8;

    f32x16 acc[4] = {};

#pragma unroll
    for (int ks = 0; ks < 8; ks++) {
        const float* p = xrow + ks * 16;
        float4 fa = *(const float4*)p;
        float4 fb = *(const float4*)(p + 4);
        float f[8] = {fa.x, fa.y, fa.z, fa.w, fb.x, fb.y, fb.z, fb.w};
        bf16x8 ahi, alo;
#pragma unroll
        for (int j = 0; j < 8; j++) {
            unsigned u = __float_as_uint(f[j]);
            unsigned hb = u & 0xFFFF0000u;
            ahi[j] = (short)(u >> 16);
            float l = f[j] - __uint_as_float(hb);
            alo[j] = (short)(__float_as_uint(l) >> 16);
        }
#pragma unroll
        for (int ct = 0; ct < 4; ct++) {
            bf16x8 bhi = *(const bf16x8*)(Ws + (size_t)(((ks * 4 + ct) * 64) + lane) * 8);
            bf16x8 blo = *(const bf16x8*)(Ws + (size_t)(((ks * 4 + ct + 32) * 64) + lane) * 8);
            acc[ct] = __builtin_amdgcn_mfma_f32_32x32x16_bf16(ahi, bhi, acc[ct], 0, 0, 0);
            acc[ct] = __builtin_amdgcn_mfma_f32_32x32x16_bf16(ahi, blo, acc[ct], 0, 0, 0);
            acc[ct] = __builtin_amdgcn_mfma_f32_32x32x16_bf16(alo, bhi, acc[ct], 0, 0, 0);
        }
    }

    // C/D layout (verified m74/m101): col=lane&31, row=(r&3)+8*(r>>2)+4*(lane>>5)
    const int col0 = lane & 31;
    const int rbase = row0 + 4 * (lane >> 5);
#pragma unroll
    for (int ct = 0; ct < 4; ct++) {
#pragma unroll
        for (int r = 0; r < 16; r++) {
            int row = rbase + (r & 3) + 8 * (r >> 2);
            if (row < M) H[(size_t)row * D + ct * 32 + col0] = (h16)acc[ct][r];
        }
    }
}

// ---------------- aggregation ----------------
// out[i] = dinv[i]*(sum_e w_e*h16[src_e] + dinv[i]*h16[i]) + b ; w_e packed in csr2
__global__ __launch_bounds__(256) void agg_kernel(const h16* __restrict__ H,
                                                  const float* __restrict__ dinv,
                                                  const int* __restrict__ rowstart,
                                                  const int2* __restrict__ csr2,
                                                  const float* __restrict__ bias,
                                                  float* __restrict__ OUT,
                                                  int n, int do_relu, int zero0) {
    int node = blockIdx.x * 4 + (threadIdx.x >> 6);
    if (node >= n) return;
    int lane = threadIdx.x & 63;
    int col = lane * 2;

    float di = dinv[node];
    h16x2 hs = *(const h16x2*)(H + (size_t)node * D + col);
    float ax = di * (float)hs[0];
    float ay = di * (float)hs[1];
    float bx = 0.f, by = 0.f;

    int s = rowstart[node];
    int e = rowstart[node + 1];
    int p = s;
    for (; p + 8 <= e; p += 8) {
        int2 sw[8];
#pragma unroll
        for (int j = 0; j < 8; j++) sw[j] = csr2[p + j];
        h16x2 hv[8];
#pragma unroll
        for (int j = 0; j < 8; j++)
            hv[j] = *(const h16x2*)(H + (size_t)sw[j].x * D + col);
#pragma unroll
        for (int j = 0; j < 8; j++) {
            float w = __int_as_float(sw[j].y);
            if (j & 1) { bx = fmaf(w, (float)hv[j][0], bx); by = fmaf(w, (float)hv[j][1], by); }
            else       { ax = fmaf(w, (float)hv[j][0], ax); ay = fmaf(w, (float)hv[j][1], ay); }
        }
    }
    for (; p + 4 <= e; p += 4) {
        int2 sw[4];
#pragma unroll
        for (int j = 0; j < 4; j++) sw[j] = csr2[p + j];
#pragma unroll
        for (int j = 0; j < 4; j++) {
            float w = __int_as_float(sw[j].y);
            h16x2 hv = *(const h16x2*)(H + (size_t)sw[j].x * D + col);
            if (j & 1) { bx = fmaf(w, (float)hv[0], bx); by = fmaf(w, (float)hv[1], by); }
            else       { ax = fmaf(w, (float)hv[0], ax); ay = fmaf(w, (float)hv[1], ay); }
        }
    }
    for (; p < e; p++) {
        int2 sw = csr2[p];
        float w = __int_as_float(sw.y);
        h16x2 hv = *(const h16x2*)(H + (size_t)sw.x * D + col);
        ax = fmaf(w, (float)hv[0], ax);
        ay = fmaf(w, (float)hv[1], ay);
    }
    ax += bx; ay += by;

    float2 b = *(const float2*)(bias + col);
    float rx = fmaf(di, ax, b.x);
    float ry = fmaf(di, ay, b.y);
    if (do_relu) { rx = fmaxf(rx, 0.f); ry = fmaxf(ry, 0.f); }
    if (zero0 && node == 0) { rx = 0.f; ry = 0.f; }
    *(float2*)(OUT + (size_t)node * D + col) = make_float2(rx, ry);
}

// ---------------- launch ----------------

extern "C" void kernel_launch(void* const* d_in, const int* in_sizes, int n_in,
                              void* d_out, int out_size, void* d_ws, size_t ws_size,
                              hipStream_t stream) {
    const float* emb = (const float*)d_in[0];
    const float* W1  = (const float*)d_in[1];
    const float* b1  = (const float*)d_in[2];
    const float* W2  = (const float*)d_in[3];
    const float* b2  = (const float*)d_in[4];
    const float* W3  = (const float*)d_in[5];
    const float* b3  = (const float*)d_in[6];
    const int*   ei  = (const int*)d_in[7];

    const int E = in_sizes[7] / 2;
    const int* srcA = ei;
    const int* dstA = ei + E;
    float* out = (float*)d_out;

    char* ws = (char*)d_ws;
    size_t off = 0;
    auto alloc = [&](size_t bytes) -> void* {
        void* p = ws + off;
        off = (off + bytes + 255) & ~(size_t)255;
        return p;
    };
    h16* h      = (h16*)alloc((size_t)NN * D * 2);
    float* xb   = (float*)alloc((size_t)NN * D * 4);
    float* dinv = (float*)alloc((size_t)NN * 4);
    int* cnt      = (int*)alloc((size_t)(NN + 1) * 4);
    int* rowstart = (int*)alloc((size_t)(NN + 1) * 4);
    int* cursor   = (int*)alloc((size_t)NN * 4);
    int2* csr2    = (int2*)alloc((size_t)E * 8);
    short* wf1    = (short*)alloc(4096 * 16);
    short* wf2    = (short*)alloc(4096 * 16);
    short* wf3    = (short*)alloc(4096 * 16);
    int* bsum     = (int*)alloc(256 * 4);

    const int T = 256;
    const int n_scan = NN + 1;
    const int scan_grid = (n_scan + SCAN_BS - 1) / SCAN_BS;

    // preprocessing (7 launches)
    zero_i32<<<(NN + 1 + T - 1) / T, T, 0, stream>>>(cnt, NN + 1);
    count_kernel<<<(E + T - 1) / T, T, 0, stream>>>(dstA, cnt, E);
    scan1_kernel<<<scan_grid, SCAN_BS, 0, stream>>>(cnt, rowstart, bsum, dinv, n_scan);
    scan2_kernel<<<1, 128, 0, stream>>>(bsum, scan_grid);
    scan3_kernel<<<scan_grid, SCAN_BS, 0, stream>>>(rowstart, bsum, cursor, n_scan);
    scatter_kernel<<<(E + T - 1) / T, T, 0, stream>>>(srcA, dstA, dinv, cursor, csr2, E);
    pack_w3_kernel<<<48, T, 0, stream>>>(W1, W2, W3, wf1, wf2, wf3);

    const int gemm_grid = (NN + 127) / 128;
    const int agg_grid  = (NN + 3) / 4;

    // layer 1
    gemm_mfma<<<gemm_grid, T, 0, stream>>>(emb, wf1, h, NN);
    agg_kernel<<<agg_grid, T, 0, stream>>>(h, dinv, rowstart, csr2, b1, xb, NN, 1, 0);
    // layer 2
    gemm_mfma<<<gemm_grid, T, 0, stream>>>(xb, wf2, h, NN);
    agg_kernel<<<agg_grid, T, 0, stream>>>(h, dinv, rowstart, csr2, b2, xb, NN, 1, 0);
    // layer 3
    gemm_mfma<<<gemm_grid, T, 0, stream>>>(xb, wf3, h, NN);
    agg_kernel<<<agg_grid, T, 0, stream>>>(h, dinv, rowstart, csr2, b3, out, NN, 0, 1);
}